// Round 1
// baseline (1275.834 us; speedup 1.0000x reference)
//
#include <hip/hip_runtime.h>
#include <math.h>

#define B 4
#define C 64
#define HW 4096
#define NTILE 64
#define EPAD 68   // LDS row stride (floats): 16B-aligned, banks spread by row*4

// ws layout (floats):
//   et  : [B][HW][C]  (e transposed: et[b][i][c] = e[b][c][i])   1,048,576 floats
//   mbuf: [B][HW]                                                   16,384 floats
//   lbuf: [B][HW]                                                   16,384 floats
// total 4,325,376 bytes
static const size_t ET_ELEMS = (size_t)B * HW * C;
static const size_t BH = (size_t)B * HW;

// ---------------- Kernel A: e = W @ x + bconv, stored transposed ----------------
__global__ __launch_bounds__(256) void k_compute_e(
    const float* __restrict__ x, const float* __restrict__ W,
    const float* __restrict__ bconv, float* __restrict__ et)
{
  __shared__ float xs[C][NTILE];   // xs[c][ii]
  __shared__ float Ws[C][C + 1];   // Ws[o][c], padded -> 2-way banks on read
  const int blk = blockIdx.x;
  const int b = blk >> 6;              // HW/NTILE = 64 blocks per batch
  const int i0 = (blk & 63) * NTILE;
  const int tid = threadIdx.x;

  for (int k = tid; k < C * C; k += 256) Ws[k >> 6][k & 63] = W[k];
  for (int k = tid; k < C * NTILE; k += 256) {
    int c = k >> 6, ii = k & 63;
    xs[c][ii] = x[((size_t)b * C + c) * HW + i0 + ii];
  }
  __syncthreads();

  const int o = tid & 63;      // output channel (consecutive lanes -> coalesced store)
  const int ig = tid >> 6;     // 0..3 : group of 16 spatial positions
  float acc[16];
  float bv = bconv[o];
  #pragma unroll
  for (int k = 0; k < 16; ++k) acc[k] = bv;
  for (int c = 0; c < C; ++c) {
    float w = Ws[o][c];
    #pragma unroll
    for (int k = 0; k < 16; ++k) acc[k] = fmaf(w, xs[c][ig * 16 + k], acc[k]);
  }
  #pragma unroll
  for (int k = 0; k < 16; ++k) {
    int ii = ig * 16 + k;
    et[((size_t)b * HW + i0 + ii) * C + o] = acc[k];
  }
}

// ---------------- Kernel B: row softmax stats (m_i, l_i) ----------------
// block = (batch b, 64 rows i). Threads: r = tid/4 row, jq = tid%4 column quarter.
__global__ __launch_bounds__(256) void k_stats(
    const float* __restrict__ et, float* __restrict__ mbuf, float* __restrict__ lbuf)
{
  __shared__ __align__(16) float ei[NTILE][EPAD];
  __shared__ __align__(16) float ej[NTILE][EPAD];
  const int blk = blockIdx.x;
  const int b = blk >> 6;
  const int i0 = (blk & 63) * NTILE;
  const int tid = threadIdx.x;
  const int r = tid >> 2;
  const int jq = tid & 3;

  for (int k = tid; k < NTILE * C; k += 256)
    ei[k >> 6][k & 63] = et[((size_t)b * HW + i0 + (k >> 6)) * C + (k & 63)];

  float m = -INFINITY, l = 0.f;

  for (int jt = 0; jt < HW / NTILE; ++jt) {
    __syncthreads();   // prev tile's readers done before overwrite
    for (int k = tid; k < NTILE * C; k += 256)
      ej[k >> 6][k & 63] = et[((size_t)b * HW + jt * NTILE + (k >> 6)) * C + (k & 63)];
    __syncthreads();

    float s[16];
    #pragma unroll
    for (int q = 0; q < 16; ++q) s[q] = 0.f;
    #pragma unroll
    for (int c4 = 0; c4 < C / 4; ++c4) {
      float4 a = *(const float4*)&ei[r][c4 * 4];
      #pragma unroll
      for (int q = 0; q < 16; ++q) {
        float4 bb = *(const float4*)&ej[jq * 16 + q][c4 * 4];
        s[q] = fmaf(a.x, bb.x, s[q]);
        s[q] = fmaf(a.y, bb.y, s[q]);
        s[q] = fmaf(a.z, bb.z, s[q]);
        s[q] = fmaf(a.w, bb.w, s[q]);
      }
    }
    float tm = s[0];
    #pragma unroll
    for (int q = 1; q < 16; ++q) tm = fmaxf(tm, s[q]);
    float nm = fmaxf(m, tm);
    l *= __expf(m - nm);
    #pragma unroll
    for (int q = 0; q < 16; ++q) l += __expf(s[q] - nm);
    m = nm;
  }

  // merge the 4 column-quarter lanes of each row (lanes 4r..4r+3, same wave)
  #pragma unroll
  for (int off = 1; off <= 2; off <<= 1) {
    float om = __shfl_xor(m, off);
    float ol = __shfl_xor(l, off);
    float nm = fmaxf(m, om);
    l = l * __expf(m - nm) + ol * __expf(om - nm);
    m = nm;
  }
  if (jq == 0) {
    mbuf[(size_t)b * HW + i0 + r] = m;
    lbuf[(size_t)b * HW + i0 + r] = l;
  }
}

// ---------------- Kernel C: final[c,j] = sum_i e[c,i] * P[i,j]; out = final + x ----
// block = (batch b, 64 columns j). Score phase: r=tid/4, jq=tid%4 (like k_stats).
// Accumulate phase: jj=tid%64 column, cg=tid/64 channel group (16 channels each).
__global__ __launch_bounds__(256) void k_out(
    const float* __restrict__ et, const float* __restrict__ mbuf,
    const float* __restrict__ lbuf, const float* __restrict__ x,
    float* __restrict__ out)
{
  __shared__ __align__(16) float ejs[NTILE][EPAD];  // block's j columns: et[j][c]
  __shared__ __align__(16) float eis[NTILE][EPAD];  // current i tile
  __shared__ __align__(16) float ps[NTILE][EPAD];   // P[i][j] tile
  __shared__ float ms[NTILE];
  __shared__ float rl[NTILE];
  const int blk = blockIdx.x;
  const int b = blk >> 6;
  const int j0 = (blk & 63) * NTILE;
  const int tid = threadIdx.x;
  const int r = tid >> 2;
  const int jq = tid & 3;
  const int jj = tid & 63;
  const int cg = tid >> 6;

  for (int k = tid; k < NTILE * C; k += 256)
    ejs[k >> 6][k & 63] = et[((size_t)b * HW + j0 + (k >> 6)) * C + (k & 63)];

  float acc[16];
  #pragma unroll
  for (int k = 0; k < 16; ++k) acc[k] = 0.f;

  for (int it = 0; it < HW / NTILE; ++it) {
    __syncthreads();   // prev accumulate done before overwriting eis/ps
    for (int k = tid; k < NTILE * C; k += 256)
      eis[k >> 6][k & 63] = et[((size_t)b * HW + it * NTILE + (k >> 6)) * C + (k & 63)];
    if (tid < NTILE) {
      float lv = lbuf[(size_t)b * HW + it * NTILE + tid];
      ms[tid] = mbuf[(size_t)b * HW + it * NTILE + tid];
      rl[tid] = 1.0f / lv;
    }
    __syncthreads();

    // score tile: s[i=r][j=jq*16+q] = dot_c(eis[r], ejs[j]); p = exp(s-m_i)/l_i
    {
      float s[16];
      #pragma unroll
      for (int q = 0; q < 16; ++q) s[q] = 0.f;
      #pragma unroll
      for (int c4 = 0; c4 < C / 4; ++c4) {
        float4 a = *(const float4*)&eis[r][c4 * 4];
        #pragma unroll
        for (int q = 0; q < 16; ++q) {
          float4 bb = *(const float4*)&ejs[jq * 16 + q][c4 * 4];
          s[q] = fmaf(a.x, bb.x, s[q]);
          s[q] = fmaf(a.y, bb.y, s[q]);
          s[q] = fmaf(a.z, bb.z, s[q]);
          s[q] = fmaf(a.w, bb.w, s[q]);
        }
      }
      float mv = ms[r], rv = rl[r];
      #pragma unroll
      for (int q = 0; q < 16; ++q)
        ps[r][jq * 16 + q] = __expf(s[q] - mv) * rv;
    }
    __syncthreads();

    // acc[c][jj] += sum_ii eis[ii][c] * ps[ii][jj]
    #pragma unroll 4
    for (int ii = 0; ii < NTILE; ++ii) {
      float pv = ps[ii][jj];
      float4 e0 = *(const float4*)&eis[ii][cg * 16 + 0];
      float4 e1 = *(const float4*)&eis[ii][cg * 16 + 4];
      float4 e2 = *(const float4*)&eis[ii][cg * 16 + 8];
      float4 e3 = *(const float4*)&eis[ii][cg * 16 + 12];
      acc[0]  = fmaf(e0.x, pv, acc[0]);
      acc[1]  = fmaf(e0.y, pv, acc[1]);
      acc[2]  = fmaf(e0.z, pv, acc[2]);
      acc[3]  = fmaf(e0.w, pv, acc[3]);
      acc[4]  = fmaf(e1.x, pv, acc[4]);
      acc[5]  = fmaf(e1.y, pv, acc[5]);
      acc[6]  = fmaf(e1.z, pv, acc[6]);
      acc[7]  = fmaf(e1.w, pv, acc[7]);
      acc[8]  = fmaf(e2.x, pv, acc[8]);
      acc[9]  = fmaf(e2.y, pv, acc[9]);
      acc[10] = fmaf(e2.z, pv, acc[10]);
      acc[11] = fmaf(e2.w, pv, acc[11]);
      acc[12] = fmaf(e3.x, pv, acc[12]);
      acc[13] = fmaf(e3.y, pv, acc[13]);
      acc[14] = fmaf(e3.z, pv, acc[14]);
      acc[15] = fmaf(e3.w, pv, acc[15]);
    }
  }

  #pragma unroll
  for (int k = 0; k < 16; ++k) {
    int c = cg * 16 + k;
    size_t idx = ((size_t)b * C + c) * HW + j0 + jj;
    out[idx] = acc[k] + x[idx];
  }
}

extern "C" void kernel_launch(void* const* d_in, const int* in_sizes, int n_in,
                              void* d_out, int out_size, void* d_ws, size_t ws_size,
                              hipStream_t stream) {
  const float* x = (const float*)d_in[0];
  const float* W = (const float*)d_in[1];
  const float* bconv = (const float*)d_in[2];
  float* out = (float*)d_out;
  float* et = (float*)d_ws;                 // needs ~4.2 MB of ws
  float* mbuf = et + ET_ELEMS;
  float* lbuf = mbuf + BH;

  const int nblk = B * (HW / NTILE);        // 256
  k_compute_e<<<dim3(nblk), dim3(256), 0, stream>>>(x, W, bconv, et);
  k_stats<<<dim3(nblk), dim3(256), 0, stream>>>(et, mbuf, lbuf);
  k_out<<<dim3(nblk), dim3(256), 0, stream>>>(et, mbuf, lbuf, x, out);
}

// Round 2
// 220.415 us; speedup vs baseline: 5.7883x; 5.7883x over previous
//
#include <hip/hip_runtime.h>
#include <math.h>

#define B 4
#define C 64
#define HW 4096

typedef _Float16 f16;
typedef f16 f16x8 __attribute__((ext_vector_type(8)));
typedef float f32x4 __attribute__((ext_vector_type(4)));

#define MFMA16(a, b, c) __builtin_amdgcn_mfma_f32_16x16x32_f16(a, b, c, 0, 0, 0)

// ws layout:
//   et16 : [B][HW][C] f16   (e transposed, i-major)  2 MB
//   ec16 : [B][C][HW] f16   (e, c-major)             2 MB
//   mbuf : [B][HW] f32      (m_i = s_ii shift)       64 KB
//   rlbuf: [B][HW] f32      (1 / l_i)                64 KB

// ---------------- Kernel A: e = W @ x + bconv -> et16 (i-major) + ec16 (c-major) ----
__global__ __launch_bounds__(256) void k_e(
    const float* __restrict__ x, const float* __restrict__ W,
    const float* __restrict__ bconv, f16* __restrict__ et, f16* __restrict__ ec)
{
  __shared__ float Ws[64][65];
  __shared__ float xs[64][64];
  __shared__ f16 es[64][72];
  const int blk = blockIdx.x;
  const int b = blk >> 6;
  const int i0 = (blk & 63) * 64;
  const int tid = threadIdx.x;

  for (int k = tid; k < 64 * 64; k += 256) Ws[k >> 6][k & 63] = W[k];
  for (int k = tid; k < 64 * 64; k += 256)
    xs[k >> 6][k & 63] = x[((size_t)b * C + (k >> 6)) * HW + i0 + (k & 63)];
  __syncthreads();

  const int o = tid & 63;    // output channel (lane-varying -> coalesced et store)
  const int ig = tid >> 6;   // spatial group
  float acc[16];
  float bv = bconv[o];
  #pragma unroll
  for (int k = 0; k < 16; ++k) acc[k] = bv;
  for (int c = 0; c < C; ++c) {
    float wv = Ws[o][c];
    #pragma unroll
    for (int k = 0; k < 16; ++k) acc[k] = fmaf(wv, xs[c][ig * 16 + k], acc[k]);
  }
  #pragma unroll
  for (int k = 0; k < 16; ++k) {
    int ii = ig * 16 + k;
    f16 v = (f16)acc[k];
    et[((size_t)b * HW + i0 + ii) * C + o] = v;
    es[o][ii] = v;
  }
  __syncthreads();
  const int ii = tid & 63, og = tid >> 6;
  #pragma unroll
  for (int k = 0; k < 16; ++k) {
    int oo = og * 16 + k;
    ec[((size_t)b * C + oo) * HW + i0 + ii] = es[oo][ii];
  }
}

// ---------------- Kernel B: m_i = s_ii, rl_i = 1 / sum_j exp(s_ij - s_ii) ---------
// grid: (b, i-tile of 64). block: 1024 threads = 16 waves; wave wv walks j-tiles wv+16t.
__global__ __launch_bounds__(1024) void k_stats(
    const f16* __restrict__ et, float* __restrict__ mbuf, float* __restrict__ rlbuf)
{
  __shared__ float msL[64];
  __shared__ float lpart[16][65];
  const int blk = blockIdx.x;
  const int b = blk >> 6;
  const int i0 = (blk & 63) * 64;
  const int tid = threadIdx.x;
  const int wv = tid >> 6;
  const int lane = tid & 63;
  const int lr = lane & 15, lg = lane >> 4;
  const f16* etb = et + (size_t)b * HW * C;

  // A-fragments for the block's 64 i-rows (4 subtiles x 2 K-chunks), hoisted
  f16x8 af[4][2];
  #pragma unroll
  for (int is = 0; is < 4; ++is)
    #pragma unroll
    for (int kc = 0; kc < 2; ++kc)
      af[is][kc] = *(const f16x8*)(etb + (size_t)(i0 + is * 16 + lr) * C + kc * 32 + lg * 8);

  // phase 1: waves 0..3 compute the diagonal subtile -> s_ii
  if (wv < 4) {
    int j0 = i0 + wv * 16;
    f16x8 b0 = *(const f16x8*)(etb + (size_t)(j0 + lr) * C + lg * 8);
    f16x8 b1 = *(const f16x8*)(etb + (size_t)(j0 + lr) * C + 32 + lg * 8);
    f32x4 z = {0.f, 0.f, 0.f, 0.f};
    f32x4 D = MFMA16(af[wv][0], b0, z);
    D = MFMA16(af[wv][1], b1, D);
    #pragma unroll
    for (int r = 0; r < 4; ++r)
      if (lr == lg * 4 + r) {
        msL[wv * 16 + lg * 4 + r] = D[r];
        mbuf[(size_t)b * HW + i0 + wv * 16 + lg * 4 + r] = D[r];
      }
  }
  __syncthreads();

  float msv[4][4];
  #pragma unroll
  for (int is = 0; is < 4; ++is)
    #pragma unroll
    for (int r = 0; r < 4; ++r) msv[is][r] = msL[is * 16 + lg * 4 + r];

  float lacc[4][4] = {};
  for (int t = 0; t < 16; ++t) {
    int j0 = (wv + 16 * t) * 16;
    f16x8 b0 = *(const f16x8*)(etb + (size_t)(j0 + lr) * C + lg * 8);
    f16x8 b1 = *(const f16x8*)(etb + (size_t)(j0 + lr) * C + 32 + lg * 8);
    #pragma unroll
    for (int is = 0; is < 4; ++is) {
      f32x4 z = {0.f, 0.f, 0.f, 0.f};
      f32x4 D = MFMA16(af[is][0], b0, z);
      D = MFMA16(af[is][1], b1, D);
      #pragma unroll
      for (int r = 0; r < 4; ++r) lacc[is][r] += __expf(D[r] - msv[is][r]);
    }
  }

  // reduce across the 16 j-columns (lanes lg*16 .. lg*16+15)
  #pragma unroll
  for (int m = 1; m < 16; m <<= 1)
    #pragma unroll
    for (int is = 0; is < 4; ++is)
      #pragma unroll
      for (int r = 0; r < 4; ++r) lacc[is][r] += __shfl_xor(lacc[is][r], m);

  if (lr == 0)
    #pragma unroll
    for (int is = 0; is < 4; ++is)
      #pragma unroll
      for (int r = 0; r < 4; ++r) lpart[wv][is * 16 + lg * 4 + r] = lacc[is][r];
  __syncthreads();

  if (tid < 64) {
    float s = 0.f;
    for (int ww = 0; ww < 16; ++ww) s += lpart[ww][tid];
    rlbuf[(size_t)b * HW + i0 + tid] = 1.0f / s;
  }
}

// ---------------- Kernel C: final[c, j] = sum_i e[c,i] P[i,j]; out = final + x ------
// grid: (b, j-tile of 16) = 1024 blocks. block: 256 threads = 4 waves.
// Per i-tile: wave wv computes score subtile isub=wv -> P -> pt LDS; then PV with cgroup=wv.
__global__ __launch_bounds__(256) void k_out(
    const f16* __restrict__ et, const f16* __restrict__ ec,
    const float* __restrict__ mbuf, const float* __restrict__ rlbuf,
    const float* __restrict__ x, float* __restrict__ out)
{
  __shared__ f16 pt[16][72];   // P transposed: pt[j][i], stride 144 B (16B-aligned, spread banks)
  const int blk = blockIdx.x;
  const int b = blk >> 8;
  const int j0 = (blk & 255) * 16;
  const int tid = threadIdx.x;
  const int wv = tid >> 6;
  const int lane = tid & 63;
  const int lr = lane & 15, lg = lane >> 4;
  const f16* etb = et + (size_t)b * HW * C;
  const f16* ecb = ec + (size_t)b * C * HW;
  const float* mb = mbuf + (size_t)b * HW;
  const float* rb = rlbuf + (size_t)b * HW;

  // score B-fragments (the block's 16 j-columns) — fixed across the i-loop
  f16x8 bj0 = *(const f16x8*)(etb + (size_t)(j0 + lr) * C + lg * 8);
  f16x8 bj1 = *(const f16x8*)(etb + (size_t)(j0 + lr) * C + 32 + lg * 8);

  f32x4 acc = {0.f, 0.f, 0.f, 0.f};

  for (int it = 0; it < 64; ++it) {
    const int i0 = it * 64;
    // scores: S[i0 + wv*16 + row][j0 + col]
    f16x8 a0 = *(const f16x8*)(etb + (size_t)(i0 + wv * 16 + lr) * C + lg * 8);
    f16x8 a1 = *(const f16x8*)(etb + (size_t)(i0 + wv * 16 + lr) * C + 32 + lg * 8);
    f32x4 z = {0.f, 0.f, 0.f, 0.f};
    f32x4 S = MFMA16(a0, bj0, z);
    S = MFMA16(a1, bj1, S);
    float4 mv = *(const float4*)&mb[i0 + wv * 16 + lg * 4];
    float4 rv = *(const float4*)&rb[i0 + wv * 16 + lg * 4];

    __syncthreads();   // prev iteration's PV reads of pt are done
    pt[lr][wv * 16 + lg * 4 + 0] = (f16)(__expf(S[0] - mv.x) * rv.x);
    pt[lr][wv * 16 + lg * 4 + 1] = (f16)(__expf(S[1] - mv.y) * rv.y);
    pt[lr][wv * 16 + lg * 4 + 2] = (f16)(__expf(S[2] - mv.z) * rv.z);
    pt[lr][wv * 16 + lg * 4 + 3] = (f16)(__expf(S[3] - mv.w) * rv.w);
    __syncthreads();

    // PV: acc[c = wv*16 + row][j0 + col] += sum_i e[c,i] P[i,j]
    f16x8 apv0 = *(const f16x8*)(ecb + (size_t)(wv * 16 + lr) * HW + i0 + lg * 8);
    f16x8 apv1 = *(const f16x8*)(ecb + (size_t)(wv * 16 + lr) * HW + i0 + 32 + lg * 8);
    f16x8 bp0 = *(const f16x8*)(&pt[lr][lg * 8]);
    f16x8 bp1 = *(const f16x8*)(&pt[lr][32 + lg * 8]);
    acc = MFMA16(apv0, bp0, acc);
    acc = MFMA16(apv1, bp1, acc);
  }

  #pragma unroll
  for (int r = 0; r < 4; ++r) {
    size_t idx = ((size_t)b * C + wv * 16 + lg * 4 + r) * HW + j0 + lr;
    out[idx] = acc[r] + x[idx];
  }
}

extern "C" void kernel_launch(void* const* d_in, const int* in_sizes, int n_in,
                              void* d_out, int out_size, void* d_ws, size_t ws_size,
                              hipStream_t stream) {
  const float* x = (const float*)d_in[0];
  const float* W = (const float*)d_in[1];
  const float* bconv = (const float*)d_in[2];
  float* out = (float*)d_out;

  f16* et16 = (f16*)d_ws;
  f16* ec16 = et16 + (size_t)B * HW * C;
  float* mbuf = (float*)(ec16 + (size_t)B * HW * C);
  float* rlbuf = mbuf + (size_t)B * HW;

  k_e<<<dim3(B * (HW / 64)), dim3(256), 0, stream>>>(x, W, bconv, et16, ec16);
  k_stats<<<dim3(B * (HW / 64)), dim3(1024), 0, stream>>>(et16, mbuf, rlbuf);
  k_out<<<dim3(B * (HW / 16)), dim3(256), 0, stream>>>(et16, ec16, mbuf, rlbuf, x, out);
}

// Round 3
// 104.851 us; speedup vs baseline: 12.1681x; 2.1022x over previous
//
#include <hip/hip_runtime.h>
#include <math.h>

#define B 4
#define C 64
#define HW 4096

typedef _Float16 f16;
typedef f16 f16x8 __attribute__((ext_vector_type(8)));
typedef f16 f16x4 __attribute__((ext_vector_type(4)));
typedef float f32x4 __attribute__((ext_vector_type(4)));

#define MFMA16(a, b, c) __builtin_amdgcn_mfma_f32_16x16x32_f16(a, b, c, 0, 0, 0)

// ws layout:
//   et16 : [B][HW][C] f16   (e transposed, i-major; score A and B frags)  2 MB
//   ec16 : [B][C][HW] f16   (e, c-major; PV A frags)                      2 MB
//   mbuf : [B][HW] f32      (m_i = s_ii softmax shift)                    64 KB
//   rlbuf: [B][HW] f32      (1 / l_i)                                     64 KB

// ---------------- Kernel A: e = W @ x + bconv -> et16 (i-major) + ec16 (c-major) ----
__global__ __launch_bounds__(256) void k_e(
    const float* __restrict__ x, const float* __restrict__ W,
    const float* __restrict__ bconv, f16* __restrict__ et, f16* __restrict__ ec)
{
  __shared__ float Ws[64][65];
  __shared__ float xs[64][64];
  __shared__ f16 es[64][72];
  const int blk = blockIdx.x;
  const int b = blk >> 6;
  const int i0 = (blk & 63) * 64;
  const int tid = threadIdx.x;

  for (int k = tid; k < 64 * 64; k += 256) Ws[k >> 6][k & 63] = W[k];
  for (int k = tid; k < 64 * 64; k += 256)
    xs[k >> 6][k & 63] = x[((size_t)b * C + (k >> 6)) * HW + i0 + (k & 63)];
  __syncthreads();

  const int o = tid & 63;
  const int ig = tid >> 6;
  float acc[16];
  float bv = bconv[o];
  #pragma unroll
  for (int k = 0; k < 16; ++k) acc[k] = bv;
  for (int c = 0; c < C; ++c) {
    float wv = Ws[o][c];
    #pragma unroll
    for (int k = 0; k < 16; ++k) acc[k] = fmaf(wv, xs[c][ig * 16 + k], acc[k]);
  }
  #pragma unroll
  for (int k = 0; k < 16; ++k) {
    int ii = ig * 16 + k;
    f16 v = (f16)acc[k];
    et[((size_t)b * HW + i0 + ii) * C + o] = v;
    es[o][ii] = v;
  }
  __syncthreads();
  const int ii = tid & 63, og = tid >> 6;
  #pragma unroll
  for (int k = 0; k < 16; ++k) {
    int oo = og * 16 + k;
    ec[((size_t)b * C + oo) * HW + i0 + ii] = es[oo][ii];
  }
}

// ---------------- Kernel B: m_i = s_ii, rl_i = 1/sum_j exp(s_ij - s_ii) -------------
// 256 blocks (b, 64-row i-block) x 512 threads (8 waves). Wave wv: j-chunks wv+8t (32 j each).
__global__ __launch_bounds__(512) void k_stats(
    const f16* __restrict__ et, float* __restrict__ mbuf, float* __restrict__ rlbuf)
{
  __shared__ float mdiag[64];
  __shared__ float lpart[8][68];
  const int blk = blockIdx.x;
  const int b = blk >> 6;
  const int i0 = (blk & 63) * 64;
  const int tid = threadIdx.x;
  const int wv = tid >> 6;
  const int lane = tid & 63;
  const int lr = lane & 15, lg = lane >> 4;
  const f16* etb = et + (size_t)b * HW * C;

  // A-fragments: the block's 64 i-rows (4 subtiles x 2 K-chunks)
  f16x8 a[4][2];
  #pragma unroll
  for (int is = 0; is < 4; ++is)
    #pragma unroll
    for (int kc = 0; kc < 2; ++kc)
      a[is][kc] = *(const f16x8*)(etb + (size_t)(i0 + is * 16 + lr) * C + kc * 32 + lg * 8);

  // diagonal s_ii: wave 0 only (A-frag == B-frag layout for the diagonal tile)
  if (wv == 0) {
    #pragma unroll
    for (int is = 0; is < 4; ++is) {
      f32x4 z = {0.f, 0.f, 0.f, 0.f};
      f32x4 D = MFMA16(a[is][0], a[is][0], z);
      D = MFMA16(a[is][1], a[is][1], D);
      #pragma unroll
      for (int r = 0; r < 4; ++r)
        if (lr == lg * 4 + r) mdiag[is * 16 + lr] = D[r];
    }
  }
  __syncthreads();

  float ms[4][4];
  #pragma unroll
  for (int is = 0; is < 4; ++is)
    #pragma unroll
    for (int r = 0; r < 4; ++r) ms[is][r] = mdiag[is * 16 + lg * 4 + r];

  float lacc[4][4] = {};
  for (int t = 0; t < 16; ++t) {
    const int j0 = (wv + 8 * t) * 32;
    f16x8 bj[2][2];
    #pragma unroll
    for (int js = 0; js < 2; ++js)
      #pragma unroll
      for (int kc = 0; kc < 2; ++kc)
        bj[js][kc] = *(const f16x8*)(etb + (size_t)(j0 + js * 16 + lr) * C + kc * 32 + lg * 8);
    #pragma unroll
    for (int js = 0; js < 2; ++js) {
      #pragma unroll
      for (int is = 0; is < 4; ++is) {
        f32x4 z = {0.f, 0.f, 0.f, 0.f};
        f32x4 S = MFMA16(a[is][0], bj[js][0], z);
        S = MFMA16(a[is][1], bj[js][1], S);
        #pragma unroll
        for (int r = 0; r < 4; ++r) lacc[is][r] += __expf(S[r] - ms[is][r]);
      }
    }
  }

  // reduce over the 16 j-columns held by lanes with the same lg
  #pragma unroll
  for (int m = 1; m < 16; m <<= 1)
    #pragma unroll
    for (int is = 0; is < 4; ++is)
      #pragma unroll
      for (int r = 0; r < 4; ++r) lacc[is][r] += __shfl_xor(lacc[is][r], m);

  if (lr == 0)
    #pragma unroll
    for (int is = 0; is < 4; ++is)
      #pragma unroll
      for (int r = 0; r < 4; ++r) lpart[wv][is * 16 + lg * 4 + r] = lacc[is][r];
  __syncthreads();

  if (tid < 64) {
    float l = 0.f;
    #pragma unroll
    for (int w = 0; w < 8; ++w) l += lpart[w][tid];
    rlbuf[(size_t)b * HW + i0 + tid] = 1.0f / l;
    mbuf[(size_t)b * HW + i0 + tid] = mdiag[tid];
  }
}

// ---------------- Kernel C: out[c,j] = sum_i e[c,i] P[i,j] + x ----------------------
// 256 blocks (b, 64-j block) x 512 threads = 8 waves = {jw in 0..1} x {is in 0..3}.
// Wave owns 32 j end-to-end; i-chunks of 32 strided by 4. NO barriers in main loop:
// P tile is wave-private LDS (lgkmcnt ordering only).
#define LDSJ 40   // f16 row stride for P tile: 80 B, 16B-aligned, spreads banks
__global__ __launch_bounds__(512) void k_out(
    const f16* __restrict__ et, const f16* __restrict__ ec,
    const float* __restrict__ mbuf, const float* __restrict__ rlbuf,
    const float* __restrict__ x, float* __restrict__ out)
{
  __shared__ f16 pt[8][32 * LDSJ];
  __shared__ float red[2][2][64][33];
  const int blk = blockIdx.x;
  const int b = blk >> 6;
  const int j0 = (blk & 63) * 64;
  const int tid = threadIdx.x;
  const int wv = tid >> 6;
  const int lane = tid & 63;
  const int lr = lane & 15, lg = lane >> 4;
  const int jw = wv >> 2, is = wv & 3;
  const int jbase = j0 + jw * 32;
  const f16* etb = et + (size_t)b * HW * C;
  const f16* ecb = ec + (size_t)b * C * HW;
  const float* mb = mbuf + (size_t)b * HW;
  const float* rb = rlbuf + (size_t)b * HW;
  f16* ptw = &pt[wv][0];

  // score B-fragments: this wave's 32 j-columns (2 subtiles x 2 K-chunks)
  f16x8 bj[2][2];
  #pragma unroll
  for (int js = 0; js < 2; ++js)
    #pragma unroll
    for (int kc = 0; kc < 2; ++kc)
      bj[js][kc] = *(const f16x8*)(etb + (size_t)(jbase + js * 16 + lr) * C + kc * 32 + lg * 8);

  f32x4 acc[2][4] = {};   // [js][cs]

  for (int t = 0; t < 32; ++t) {
    const int i0c = (is + 4 * t) * 32;

    // score A-fragments: 32 i-rows
    f16x8 a[2][2];
    #pragma unroll
    for (int isub = 0; isub < 2; ++isub)
      #pragma unroll
      for (int kc = 0; kc < 2; ++kc)
        a[isub][kc] = *(const f16x8*)(etb + (size_t)(i0c + isub * 16 + lr) * C + kc * 32 + lg * 8);

    // scores
    f32x4 S[2][2];   // [js][isub]
    #pragma unroll
    for (int js = 0; js < 2; ++js)
      #pragma unroll
      for (int isub = 0; isub < 2; ++isub) {
        f32x4 z = {0.f, 0.f, 0.f, 0.f};
        f32x4 s0 = MFMA16(a[isub][0], bj[js][0], z);
        S[js][isub] = MFMA16(a[isub][1], bj[js][1], s0);
      }

    // softmax factors for these 32 rows
    f32x4 mv[2], rv[2];
    #pragma unroll
    for (int isub = 0; isub < 2; ++isub) {
      mv[isub] = *(const f32x4*)(mb + i0c + isub * 16 + lg * 4);
      rv[isub] = *(const f32x4*)(rb + i0c + isub * 16 + lg * 4);
    }

    // P = exp(S - m) / l  -> wave-private LDS tile pt[j][i]
    #pragma unroll
    for (int js = 0; js < 2; ++js)
      #pragma unroll
      for (int isub = 0; isub < 2; ++isub) {
        f16x4 pv;
        #pragma unroll
        for (int r = 0; r < 4; ++r)
          pv[r] = (f16)(__expf(S[js][isub][r] - mv[isub][r]) * rv[isub][r]);
        *(f16x4*)(ptw + (js * 16 + lr) * LDSJ + isub * 16 + lg * 4) = pv;
      }

    // PV: B-frag from P tile (k = i), A-frag from ec (k = i)
    f16x8 bp0 = *(const f16x8*)(ptw + (0 * 16 + lr) * LDSJ + lg * 8);
    f16x8 bp1 = *(const f16x8*)(ptw + (1 * 16 + lr) * LDSJ + lg * 8);
    f16x8 apv[4];
    #pragma unroll
    for (int cs = 0; cs < 4; ++cs)
      apv[cs] = *(const f16x8*)(ecb + (size_t)(cs * 16 + lr) * HW + i0c + lg * 8);
    #pragma unroll
    for (int cs = 0; cs < 4; ++cs) acc[0][cs] = MFMA16(apv[cs], bp0, acc[0][cs]);
    #pragma unroll
    for (int cs = 0; cs < 4; ++cs) acc[1][cs] = MFMA16(apv[cs], bp1, acc[1][cs]);
  }

  // ---- cross-wave reduction over the 4-way i-split (per jw group) ----
  if (is >= 2) {
    float* slot = &red[jw][is - 2][lane][0];
    #pragma unroll
    for (int js = 0; js < 2; ++js)
      #pragma unroll
      for (int cs = 0; cs < 4; ++cs)
        #pragma unroll
        for (int r = 0; r < 4; ++r) slot[js * 16 + cs * 4 + r] = acc[js][cs][r];
  }
  __syncthreads();
  if (is < 2) {
    float* slot = &red[jw][is][lane][0];
    #pragma unroll
    for (int js = 0; js < 2; ++js)
      #pragma unroll
      for (int cs = 0; cs < 4; ++cs)
        #pragma unroll
        for (int r = 0; r < 4; ++r) acc[js][cs][r] += slot[js * 16 + cs * 4 + r];
  }
  __syncthreads();
  if (is == 1) {
    float* slot = &red[jw][0][lane][0];
    #pragma unroll
    for (int js = 0; js < 2; ++js)
      #pragma unroll
      for (int cs = 0; cs < 4; ++cs)
        #pragma unroll
        for (int r = 0; r < 4; ++r) slot[js * 16 + cs * 4 + r] = acc[js][cs][r];
  }
  __syncthreads();
  if (is == 0) {
    float* slot = &red[jw][0][lane][0];
    #pragma unroll
    for (int js = 0; js < 2; ++js)
      #pragma unroll
      for (int cs = 0; cs < 4; ++cs) {
        #pragma unroll
        for (int r = 0; r < 4; ++r) {
          float v = acc[js][cs][r] + slot[js * 16 + cs * 4 + r];
          int c = cs * 16 + lg * 4 + r;
          size_t idx = ((size_t)b * C + c) * HW + jbase + js * 16 + lr;
          out[idx] = v + x[idx];
        }
      }
  }
}

extern "C" void kernel_launch(void* const* d_in, const int* in_sizes, int n_in,
                              void* d_out, int out_size, void* d_ws, size_t ws_size,
                              hipStream_t stream) {
  const float* x = (const float*)d_in[0];
  const float* W = (const float*)d_in[1];
  const float* bconv = (const float*)d_in[2];
  float* out = (float*)d_out;

  f16* et16 = (f16*)d_ws;
  f16* ec16 = et16 + (size_t)B * HW * C;
  float* mbuf = (float*)(ec16 + (size_t)B * HW * C);
  float* rlbuf = mbuf + (size_t)B * HW;

  k_e<<<dim3(B * (HW / 64)), dim3(256), 0, stream>>>(x, W, bconv, et16, ec16);
  k_stats<<<dim3(B * (HW / 64)), dim3(512), 0, stream>>>(et16, mbuf, rlbuf);
  k_out<<<dim3(B * (HW / 64)), dim3(512), 0, stream>>>(et16, ec16, mbuf, rlbuf, x, out);
}

// Round 4
// 104.619 us; speedup vs baseline: 12.1951x; 1.0022x over previous
//
#include <hip/hip_runtime.h>
#include <math.h>

#define B 4
#define C 64
#define HW 4096

typedef _Float16 f16;
typedef f16 f16x8 __attribute__((ext_vector_type(8)));
typedef f16 f16x4 __attribute__((ext_vector_type(4)));
typedef float f32x4 __attribute__((ext_vector_type(4)));
typedef float f32x16 __attribute__((ext_vector_type(16)));
typedef f16x8 f16x8a __attribute__((aligned(8)));   // 8B-aligned vector (rows are 8B-aligned, not 16B)

#define MFMA16(a,b,c) __builtin_amdgcn_mfma_f32_16x16x32_f16(a,b,c,0,0,0)
#define MFMA32(a,b,c) __builtin_amdgcn_mfma_f32_32x32x16_f16(a,b,c,0,0,0)

// ws layout (total ~20.2 MB — assumes ws_size >= 21 MB):
//   et16   : [B][HW][C] f16  (e, i-major)        2 MB
//   ec16   : [B][C][HW] f16  (e, c-major)        2 MB
//   mbuf   : [B][HW] f32     (m_i = s_ii)        64 KB
//   rlbuf  : [B][HW] f32     (1/l_i)             64 KB
//   partial: [8][B][HW][C] f16  (out^T per iq)   16 MB

// XCD-affine swizzle: 256 blocks, 8 XCDs -> XCD x gets contiguous logical range.
__device__ __forceinline__ int swz_blk() {
  int raw = blockIdx.x;
  return (raw & 7) * 32 + (raw >> 3);
}

// ---------------- Kernel A: e = W @ x + bconv -> et16 (i-major) + ec16 (c-major) ----
__global__ __launch_bounds__(256) void k_e(
    const float* __restrict__ x, const float* __restrict__ W,
    const float* __restrict__ bconv, f16* __restrict__ et, f16* __restrict__ ec)
{
  __shared__ float Ws[64][65];
  __shared__ float xs[64][64];
  __shared__ f16 es[64][72];
  const int blk = swz_blk();
  const int b = blk >> 6;
  const int i0 = (blk & 63) * 64;
  const int tid = threadIdx.x;

  for (int k = tid; k < 64 * 64; k += 256) Ws[k >> 6][k & 63] = W[k];
  for (int k = tid; k < 64 * 64; k += 256)
    xs[k >> 6][k & 63] = x[((size_t)b * C + (k >> 6)) * HW + i0 + (k & 63)];
  __syncthreads();

  const int o = tid & 63;
  const int ig = tid >> 6;
  float acc[16];
  float bv = bconv[o];
  #pragma unroll
  for (int k = 0; k < 16; ++k) acc[k] = bv;
  for (int c = 0; c < C; ++c) {
    float wv = Ws[o][c];
    #pragma unroll
    for (int k = 0; k < 16; ++k) acc[k] = fmaf(wv, xs[c][ig * 16 + k], acc[k]);
  }
  #pragma unroll
  for (int k = 0; k < 16; ++k) {
    int ii = ig * 16 + k;
    f16 v = (f16)acc[k];
    et[((size_t)b * HW + i0 + ii) * C + o] = v;
    es[o][ii] = v;
  }
  __syncthreads();
  const int ii = tid & 63, og = tid >> 6;
  #pragma unroll
  for (int k = 0; k < 16; ++k) {
    int oo = og * 16 + k;
    ec[((size_t)b * C + oo) * HW + i0 + ii] = es[oo][ii];
  }
}

// ---------------- Kernel B: m_i = s_ii, rl_i = 1/sum_j exp(s_ij - s_ii) -------------
// 256 blocks (b, 64-row i-block) x 1024 thr (16 waves). Wave wv: j-chunks (wv+16t)*16.
__global__ __launch_bounds__(1024, 4) void k_stats(
    const f16* __restrict__ et, float* __restrict__ mbuf, float* __restrict__ rlbuf)
{
  __shared__ float mdiag[64];
  __shared__ float lpart[16][68];
  const int blk = swz_blk();
  const int b = blk >> 6;
  const int i0 = (blk & 63) * 64;
  const int tid = threadIdx.x;
  const int wv = tid >> 6;
  const int lane = tid & 63;
  const int lr = lane & 15, lg = lane >> 4;
  const f16* etb = et + (size_t)b * HW * C;

  // A-fragments: the block's 64 i-rows (4 subtiles x 2 K-chunks)
  f16x8 a[4][2];
  #pragma unroll
  for (int is = 0; is < 4; ++is)
    #pragma unroll
    for (int kc = 0; kc < 2; ++kc)
      a[is][kc] = *(const f16x8*)(etb + (size_t)(i0 + is * 16 + lr) * C + kc * 32 + lg * 8);

  if (wv == 0) {
    #pragma unroll
    for (int is = 0; is < 4; ++is) {
      f32x4 z = {0.f, 0.f, 0.f, 0.f};
      f32x4 D = MFMA16(a[is][0], a[is][0], z);
      D = MFMA16(a[is][1], a[is][1], D);
      #pragma unroll
      for (int r = 0; r < 4; ++r)
        if (lr == lg * 4 + r) mdiag[is * 16 + lr] = D[r];
    }
  }
  __syncthreads();

  float ms[4][4];
  #pragma unroll
  for (int is = 0; is < 4; ++is)
    #pragma unroll
    for (int r = 0; r < 4; ++r) ms[is][r] = mdiag[is * 16 + lg * 4 + r];

  float lacc[4][4] = {};
  for (int t = 0; t < 16; ++t) {
    const int j0 = (wv + 16 * t) * 16;
    f16x8 b0 = *(const f16x8*)(etb + (size_t)(j0 + lr) * C + lg * 8);
    f16x8 b1 = *(const f16x8*)(etb + (size_t)(j0 + lr) * C + 32 + lg * 8);
    #pragma unroll
    for (int is = 0; is < 4; ++is) {
      f32x4 z = {0.f, 0.f, 0.f, 0.f};
      f32x4 S = MFMA16(a[is][0], b0, z);
      S = MFMA16(a[is][1], b1, S);
      #pragma unroll
      for (int r = 0; r < 4; ++r) lacc[is][r] += __expf(S[r] - ms[is][r]);
    }
  }

  #pragma unroll
  for (int m = 1; m < 16; m <<= 1)
    #pragma unroll
    for (int is = 0; is < 4; ++is)
      #pragma unroll
      for (int r = 0; r < 4; ++r) lacc[is][r] += __shfl_xor(lacc[is][r], m);

  if (lr == 0)
    #pragma unroll
    for (int is = 0; is < 4; ++is)
      #pragma unroll
      for (int r = 0; r < 4; ++r) lpart[wv][is * 16 + lg * 4 + r] = lacc[is][r];
  __syncthreads();

  if (tid < 64) {
    float l = 0.f;
    #pragma unroll
    for (int w = 0; w < 16; ++w) l += lpart[w][tid];
    rlbuf[(size_t)b * HW + i0 + tid] = 1.0f / l;
    mbuf[(size_t)b * HW + i0 + tid] = mdiag[tid];
  }
}

// ---------------- Kernel C: partial^T[iq] += P^T . e^T  (out^T = sum_i) -------------
// 256 blocks = (b:4, jb:8 of 512 j, iq:8 of 512 i). 512 thr = 8 waves, 64 j per wave.
// Per 32-i chunk: stage et/ec chunk to LDS (dbuf, shared by all waves), 32x32x16 MFMA.
#define ETS 68   // etL row stride (f16)
#define ECS 36   // ecL row stride
#define PTS 36   // pt  row stride
__global__ __launch_bounds__(512, 2) void k_out(
    const f16* __restrict__ et, const f16* __restrict__ ec,
    const float* __restrict__ mbuf, const float* __restrict__ rlbuf,
    f16* __restrict__ partial)
{
  __shared__ __align__(16) f16 etL[2][32][ETS];   // [i][c]
  __shared__ __align__(16) f16 ecL[2][64][ECS];   // [c][i]
  __shared__ __align__(16) f16 pt[8][32][PTS];    // wave-private P^T repack [j][i]
  const int blk = swz_blk();
  const int b  = blk >> 6;
  const int jb = (blk >> 3) & 7;
  const int iq = blk & 7;
  const int tid = threadIdx.x;
  const int w = tid >> 6;
  const int lane = tid & 63;
  const int l31 = lane & 31;
  const int h = lane >> 5;
  const int jbase = jb * 512 + w * 64;
  const int ibase = iq * 512;

  const f16* etb = et + (size_t)b * HW * C;
  const f16* ecb = ec + (size_t)b * C * HW;
  const float* mb = mbuf + (size_t)b * HW;
  const float* rb = rlbuf + (size_t)b * HW;

  // score B fragments (regs, fixed): 2 j-tiles x 4 K-chunks of 16 c
  f16x8 bj[2][4];
  #pragma unroll
  for (int jt = 0; jt < 2; ++jt)
    #pragma unroll
    for (int kc = 0; kc < 4; ++kc)
      bj[jt][kc] = *(const f16x8*)(etb + (size_t)(jbase + jt * 32 + l31) * C + kc * 16 + h * 8);

  f32x16 acc[2][2] = {};   // [jt][cs] of out^T (m=j, n=c)

  // staging roles: threads 0..255 stage et chunk (32x64), 256..511 stage ec (64x32)
  const bool se = (tid < 256);
  const int sei = tid >> 3;
  const int sec = (tid & 7) * 8;
  const int scc = (tid & 255) >> 2;
  const int sci = (tid & 3) * 8;

  // prologue: stage chunk 0
  if (se) *(f16x8a*)&etL[0][sei][sec] = *(const f16x8*)(etb + (size_t)(ibase + sei) * C + sec);
  else    *(f16x8a*)&ecL[0][scc][sci] = *(const f16x8*)(ecb + (size_t)scc * HW + ibase + sci);
  __syncthreads();

  for (int t = 0; t < 16; ++t) {
    const int cur = t & 1;
    const int i0c = ibase + t * 32;

    // issue next chunk's global load early
    f16x8 sv;
    if (t < 15) {
      if (se) sv = *(const f16x8*)(etb + (size_t)(i0c + 32 + sei) * C + sec);
      else    sv = *(const f16x8*)(ecb + (size_t)scc * HW + (i0c + 32) + sci);
    }

    // softmax constants for the chunk's 32 i (reg-mapped: i = (r&3)+8*(r>>2)+4h)
    f32x4 m4[4], r4[4];
    #pragma unroll
    for (int rq = 0; rq < 4; ++rq) {
      m4[rq] = *(const f32x4*)(mb + i0c + 8 * rq + 4 * h);
      r4[rq] = *(const f32x4*)(rb + i0c + 8 * rq + 4 * h);
    }

    // PV B fragments (e^T): B[k=i][n=c] from ecL
    f16x8 bv[2][2];
    #pragma unroll
    for (int cs = 0; cs < 2; ++cs)
      #pragma unroll
      for (int kf = 0; kf < 2; ++kf)
        bv[cs][kf] = *(const f16x8a*)&ecL[cur][cs * 32 + l31][kf * 16 + h * 8];

    // score A fragments: A[m=i][k=c] from etL
    f16x8 af[4];
    #pragma unroll
    for (int kc = 0; kc < 4; ++kc)
      af[kc] = *(const f16x8a*)&etL[cur][l31][kc * 16 + h * 8];

    #pragma unroll
    for (int jt = 0; jt < 2; ++jt) {
      f32x16 z = {};
      f32x16 S = MFMA32(af[0], bj[jt][0], z);
      S = MFMA32(af[1], bj[jt][1], S);
      S = MFMA32(af[2], bj[jt][2], S);
      S = MFMA32(af[3], bj[jt][3], S);
      // P = exp(S - m_i) * rl_i  -> wave-private pt[j][i] (S lane: col j=l31, i by reg)
      #pragma unroll
      for (int rq = 0; rq < 4; ++rq) {
        f16x4 pv;
        #pragma unroll
        for (int rr = 0; rr < 4; ++rr)
          pv[rr] = (f16)(__expf(S[rq * 4 + rr] - m4[rq][rr]) * r4[rq][rr]);
        *(f16x4*)&pt[w][l31][8 * rq + 4 * h] = pv;
      }
      // read back as PV A-frags: A[m=j][k=i]
      f16x8 pa0 = *(const f16x8a*)&pt[w][l31][h * 8];
      f16x8 pa1 = *(const f16x8a*)&pt[w][l31][16 + h * 8];
      acc[jt][0] = MFMA32(pa0, bv[0][0], acc[jt][0]);
      acc[jt][1] = MFMA32(pa0, bv[1][0], acc[jt][1]);
      acc[jt][0] = MFMA32(pa1, bv[0][1], acc[jt][0]);
      acc[jt][1] = MFMA32(pa1, bv[1][1], acc[jt][1]);
    }

    // stage write for next chunk
    if (t < 15) {
      if (se) *(f16x8a*)&etL[cur ^ 1][sei][sec] = sv;
      else    *(f16x8a*)&ecL[cur ^ 1][scc][sci] = sv;
    }
    __syncthreads();
  }

  // partial[iq][b][j][c] (out^T layout -> coalesced: lanes vary c)
  f16* pb = partial + (size_t)(iq * B + b) * HW * C;
  #pragma unroll
  for (int jt = 0; jt < 2; ++jt)
    #pragma unroll
    for (int cs = 0; cs < 2; ++cs)
      #pragma unroll
      for (int r = 0; r < 16; ++r) {
        int j = jbase + jt * 32 + (r & 3) + 8 * (r >> 2) + 4 * h;
        pb[(size_t)j * C + cs * 32 + l31] = (f16)acc[jt][cs][r];
      }
}

// ---------------- Kernel D: out[c][j] = x + sum_iq partial[iq][j][c] (transpose) ----
__global__ __launch_bounds__(256) void k_reduce(
    const f16* __restrict__ partial, const float* __restrict__ x, float* __restrict__ out)
{
  __shared__ float tile[64][65];
  const int blk = swz_blk();
  const int b = blk >> 6;
  const int j0 = (blk & 63) * 64;
  const int tid = threadIdx.x;
  const int jj = tid >> 2, cq = (tid & 3) * 16;

  float a0[16] = {};
  for (int iq = 0; iq < 8; ++iq) {
    const f16* p = partial + ((size_t)(iq * B + b) * HW + j0 + jj) * C + cq;
    f16x8 v0 = *(const f16x8*)p;
    f16x8 v1 = *(const f16x8*)(p + 8);
    #pragma unroll
    for (int e = 0; e < 8; ++e) { a0[e] += (float)v0[e]; a0[8 + e] += (float)v1[e]; }
  }
  #pragma unroll
  for (int e = 0; e < 16; ++e) tile[jj][cq + e] = a0[e];
  __syncthreads();

  const int c = tid >> 2, jq = (tid & 3) * 16;
  #pragma unroll
  for (int k = 0; k < 4; ++k) {
    size_t idx = ((size_t)b * C + c) * HW + j0 + jq + k * 4;
    float4 xv = *(const float4*)(x + idx);
    float4 ov;
    ov.x = tile[jq + k * 4 + 0][c] + xv.x;
    ov.y = tile[jq + k * 4 + 1][c] + xv.y;
    ov.z = tile[jq + k * 4 + 2][c] + xv.z;
    ov.w = tile[jq + k * 4 + 3][c] + xv.w;
    *(float4*)(out + idx) = ov;
  }
}

extern "C" void kernel_launch(void* const* d_in, const int* in_sizes, int n_in,
                              void* d_out, int out_size, void* d_ws, size_t ws_size,
                              hipStream_t stream) {
  const float* x = (const float*)d_in[0];
  const float* W = (const float*)d_in[1];
  const float* bconv = (const float*)d_in[2];
  float* out = (float*)d_out;

  f16* et16 = (f16*)d_ws;
  f16* ec16 = et16 + (size_t)B * HW * C;
  float* mbuf = (float*)(ec16 + (size_t)B * HW * C);
  float* rlbuf = mbuf + (size_t)B * HW;
  f16* partial = (f16*)(rlbuf + (size_t)B * HW);   // 16 MB; ws total ~20.2 MB

  k_e<<<dim3(256), dim3(256), 0, stream>>>(x, W, bconv, et16, ec16);
  k_stats<<<dim3(256), dim3(1024), 0, stream>>>(et16, mbuf, rlbuf);
  k_out<<<dim3(256), dim3(512), 0, stream>>>(et16, ec16, mbuf, rlbuf, partial);
  k_reduce<<<dim3(256), dim3(256), 0, stream>>>(partial, x, out);
}

// Round 5
// 86.681 us; speedup vs baseline: 14.7188x; 1.2069x over previous
//
#include <hip/hip_runtime.h>
#include <math.h>

#define B 4
#define C 64
#define HW 4096

typedef _Float16 f16;
typedef f16 f16x8 __attribute__((ext_vector_type(8)));
typedef f16 f16x4 __attribute__((ext_vector_type(4)));
typedef float f32x4 __attribute__((ext_vector_type(4)));
typedef float f32x16 __attribute__((ext_vector_type(16)));
typedef f16x8 f16x8a __attribute__((aligned(8)));   // 8B-aligned vector (rows are 8B-aligned, not 16B)

#define MFMA16(a,b,c) __builtin_amdgcn_mfma_f32_16x16x32_f16(a,b,c,0,0,0)
#define MFMA32(a,b,c) __builtin_amdgcn_mfma_f32_32x32x16_f16(a,b,c,0,0,0)

// ws layout (total ~20.2 MB):
//   et16   : [B][HW][C] f16  (e, i-major)        2 MB
//   ec16   : [B][C][HW] f16  (e, c-major)        2 MB
//   mbuf   : [B][HW] f32     (m_i = s_ii)        64 KB
//   rlbuf  : [B][HW] f32     (1/l_i)             64 KB
//   partial: [8][B][HW][C] f16  (out^T per iq)   16 MB

// XCD-affine swizzle for 256-block grids (8 XCDs x 32 contiguous logical blocks).
__device__ __forceinline__ int swz_blk() {
  int raw = blockIdx.x;
  return (raw & 7) * 32 + (raw >> 3);
}
// XCD-affine swizzle for 512-block grids (8 XCDs x 64 contiguous logical blocks).
__device__ __forceinline__ int swz_blk512() {
  int raw = blockIdx.x;
  return (raw & 7) * 64 + (raw >> 3);
}

// ---------------- Kernel A: e = W @ x + bconv -> et16 (i-major) + ec16 (c-major) ----
__global__ __launch_bounds__(256) void k_e(
    const float* __restrict__ x, const float* __restrict__ W,
    const float* __restrict__ bconv, f16* __restrict__ et, f16* __restrict__ ec)
{
  __shared__ float Ws[64][65];
  __shared__ float xs[64][64];
  __shared__ f16 es[64][72];
  const int blk = swz_blk();
  const int b = blk >> 6;
  const int i0 = (blk & 63) * 64;
  const int tid = threadIdx.x;

  for (int k = tid; k < 64 * 64; k += 256) Ws[k >> 6][k & 63] = W[k];
  for (int k = tid; k < 64 * 64; k += 256)
    xs[k >> 6][k & 63] = x[((size_t)b * C + (k >> 6)) * HW + i0 + (k & 63)];
  __syncthreads();

  const int o = tid & 63;
  const int ig = tid >> 6;
  float acc[16];
  float bv = bconv[o];
  #pragma unroll
  for (int k = 0; k < 16; ++k) acc[k] = bv;
  for (int c = 0; c < C; ++c) {
    float wv = Ws[o][c];
    #pragma unroll
    for (int k = 0; k < 16; ++k) acc[k] = fmaf(wv, xs[c][ig * 16 + k], acc[k]);
  }
  #pragma unroll
  for (int k = 0; k < 16; ++k) {
    int ii = ig * 16 + k;
    f16 v = (f16)acc[k];
    et[((size_t)b * HW + i0 + ii) * C + o] = v;
    es[o][ii] = v;
  }
  __syncthreads();
  const int ii = tid & 63, og = tid >> 6;
  #pragma unroll
  for (int k = 0; k < 16; ++k) {
    int oo = og * 16 + k;
    ec[((size_t)b * C + oo) * HW + i0 + ii] = es[oo][ii];
  }
}

// ---------------- Kernel B: m_i = s_ii, rl_i = 1/sum_j exp(s_ij - s_ii) -------------
// 512 blocks = (b:4, 128 i-blocks of 32 rows) x 512 thr (8 waves).
// Small register state (~70 VGPR) -> no spills, 2 blocks/CU = 16 waves/CU.
__global__ __launch_bounds__(512) void k_stats(
    const f16* __restrict__ et, float* __restrict__ mbuf, float* __restrict__ rlbuf)
{
  __shared__ float mdiag[32];
  __shared__ float lpart[8][36];
  const int blk = swz_blk512();
  const int b = blk >> 7;
  const int i0 = (blk & 127) * 32;
  const int tid = threadIdx.x;
  const int wv = tid >> 6;
  const int lane = tid & 63;
  const int lr = lane & 15, lg = lane >> 4;
  const f16* etb = et + (size_t)b * HW * C;

  // A-fragments: the block's 32 i-rows (2 subtiles x 2 K-chunks)
  f16x8 a[2][2];
  #pragma unroll
  for (int is = 0; is < 2; ++is)
    #pragma unroll
    for (int kc = 0; kc < 2; ++kc)
      a[is][kc] = *(const f16x8*)(etb + (size_t)(i0 + is * 16 + lr) * C + kc * 32 + lg * 8);

  // diagonal s_ii (wave 0; A-frag == B-frag layout on the diagonal tile)
  if (wv == 0) {
    #pragma unroll
    for (int is = 0; is < 2; ++is) {
      f32x4 z = {0.f, 0.f, 0.f, 0.f};
      f32x4 D = MFMA16(a[is][0], a[is][0], z);
      D = MFMA16(a[is][1], a[is][1], D);
      #pragma unroll
      for (int r = 0; r < 4; ++r)
        if (lr == lg * 4 + r) mdiag[is * 16 + lr] = D[r];
    }
  }
  __syncthreads();

  float ms[2][4];
  #pragma unroll
  for (int is = 0; is < 2; ++is)
    #pragma unroll
    for (int r = 0; r < 4; ++r) ms[is][r] = mdiag[is * 16 + lg * 4 + r];

  float lacc[2][4] = {};
  for (int t = 0; t < 16; ++t) {
    const int j0 = (wv + 8 * t) * 32;
    f16x8 bj[2][2];
    #pragma unroll
    for (int js = 0; js < 2; ++js)
      #pragma unroll
      for (int kc = 0; kc < 2; ++kc)
        bj[js][kc] = *(const f16x8*)(etb + (size_t)(j0 + js * 16 + lr) * C + kc * 32 + lg * 8);
    #pragma unroll
    for (int js = 0; js < 2; ++js)
      #pragma unroll
      for (int is = 0; is < 2; ++is) {
        f32x4 z = {0.f, 0.f, 0.f, 0.f};
        f32x4 S = MFMA16(a[is][0], bj[js][0], z);
        S = MFMA16(a[is][1], bj[js][1], S);
        #pragma unroll
        for (int r = 0; r < 4; ++r) lacc[is][r] += __expf(S[r] - ms[is][r]);
      }
  }

  // reduce over the 16 j-columns held by lanes sharing lg (xor 1,2,4,8 stays in group)
  #pragma unroll
  for (int m = 1; m < 16; m <<= 1)
    #pragma unroll
    for (int is = 0; is < 2; ++is)
      #pragma unroll
      for (int r = 0; r < 4; ++r) lacc[is][r] += __shfl_xor(lacc[is][r], m);

  if (lr == 0)
    #pragma unroll
    for (int is = 0; is < 2; ++is)
      #pragma unroll
      for (int r = 0; r < 4; ++r) lpart[wv][is * 16 + lg * 4 + r] = lacc[is][r];
  __syncthreads();

  if (tid < 32) {
    float l = 0.f;
    #pragma unroll
    for (int w = 0; w < 8; ++w) l += lpart[w][tid];
    rlbuf[(size_t)b * HW + i0 + tid] = 1.0f / l;
    mbuf[(size_t)b * HW + i0 + tid] = mdiag[tid];
  }
}

// ---------------- Kernel C: partial^T[iq] += P^T . e^T  (out^T = sum_i) -------------
// 256 blocks = (b:4, jb:8 of 512 j, iq:8 of 512 i). 512 thr = 8 waves, 64 j per wave.
#define ETS 68   // etL row stride (f16)
#define ECS 36   // ecL row stride
#define PTS 36   // pt  row stride
__global__ __launch_bounds__(512, 2) void k_out(
    const f16* __restrict__ et, const f16* __restrict__ ec,
    const float* __restrict__ mbuf, const float* __restrict__ rlbuf,
    f16* __restrict__ partial)
{
  __shared__ __align__(16) f16 etL[2][32][ETS];   // [i][c]
  __shared__ __align__(16) f16 ecL[2][64][ECS];   // [c][i]
  __shared__ __align__(16) f16 pt[8][32][PTS];    // wave-private P^T repack [j][i]
  const int blk = swz_blk();
  const int b  = blk >> 6;
  const int jb = (blk >> 3) & 7;
  const int iq = blk & 7;
  const int tid = threadIdx.x;
  const int w = tid >> 6;
  const int lane = tid & 63;
  const int l31 = lane & 31;
  const int h = lane >> 5;
  const int jbase = jb * 512 + w * 64;
  const int ibase = iq * 512;

  const f16* etb = et + (size_t)b * HW * C;
  const f16* ecb = ec + (size_t)b * C * HW;
  const float* mb = mbuf + (size_t)b * HW;
  const float* rb = rlbuf + (size_t)b * HW;

  // score B fragments (regs, fixed): 2 j-tiles x 4 K-chunks of 16 c
  f16x8 bj[2][4];
  #pragma unroll
  for (int jt = 0; jt < 2; ++jt)
    #pragma unroll
    for (int kc = 0; kc < 4; ++kc)
      bj[jt][kc] = *(const f16x8*)(etb + (size_t)(jbase + jt * 32 + l31) * C + kc * 16 + h * 8);

  f32x16 acc[2][2] = {};   // [jt][cs] of out^T (m=j, n=c)

  // staging roles: threads 0..255 stage et chunk (32x64), 256..511 stage ec (64x32)
  const bool se = (tid < 256);
  const int sei = tid >> 3;
  const int sec = (tid & 7) * 8;
  const int scc = (tid & 255) >> 2;
  const int sci = (tid & 3) * 8;

  // prologue: stage chunk 0
  if (se) *(f16x8a*)&etL[0][sei][sec] = *(const f16x8*)(etb + (size_t)(ibase + sei) * C + sec);
  else    *(f16x8a*)&ecL[0][scc][sci] = *(const f16x8*)(ecb + (size_t)scc * HW + ibase + sci);
  __syncthreads();

  for (int t = 0; t < 16; ++t) {
    const int cur = t & 1;
    const int i0c = ibase + t * 32;

    // issue next chunk's global load early
    f16x8 sv;
    if (t < 15) {
      if (se) sv = *(const f16x8*)(etb + (size_t)(i0c + 32 + sei) * C + sec);
      else    sv = *(const f16x8*)(ecb + (size_t)scc * HW + (i0c + 32) + sci);
    }

    // softmax constants for the chunk's 32 i (reg-mapped: i = (r&3)+8*(r>>2)+4h)
    f32x4 m4[4], r4[4];
    #pragma unroll
    for (int rq = 0; rq < 4; ++rq) {
      m4[rq] = *(const f32x4*)(mb + i0c + 8 * rq + 4 * h);
      r4[rq] = *(const f32x4*)(rb + i0c + 8 * rq + 4 * h);
    }

    // PV B fragments (e^T): B[k=i][n=c] from ecL
    f16x8 bv[2][2];
    #pragma unroll
    for (int cs = 0; cs < 2; ++cs)
      #pragma unroll
      for (int kf = 0; kf < 2; ++kf)
        bv[cs][kf] = *(const f16x8a*)&ecL[cur][cs * 32 + l31][kf * 16 + h * 8];

    // score A fragments: A[m=i][k=c] from etL
    f16x8 af[4];
    #pragma unroll
    for (int kc = 0; kc < 4; ++kc)
      af[kc] = *(const f16x8a*)&etL[cur][l31][kc * 16 + h * 8];

    #pragma unroll
    for (int jt = 0; jt < 2; ++jt) {
      f32x16 z = {};
      f32x16 S = MFMA32(af[0], bj[jt][0], z);
      S = MFMA32(af[1], bj[jt][1], S);
      S = MFMA32(af[2], bj[jt][2], S);
      S = MFMA32(af[3], bj[jt][3], S);
      // P = exp(S - m_i) * rl_i  -> wave-private pt[j][i]
      #pragma unroll
      for (int rq = 0; rq < 4; ++rq) {
        f16x4 pv;
        #pragma unroll
        for (int rr = 0; rr < 4; ++rr)
          pv[rr] = (f16)(__expf(S[rq * 4 + rr] - m4[rq][rr]) * r4[rq][rr]);
        *(f16x4*)&pt[w][l31][8 * rq + 4 * h] = pv;
      }
      // read back as PV A-frags: A[m=j][k=i]
      f16x8 pa0 = *(const f16x8a*)&pt[w][l31][h * 8];
      f16x8 pa1 = *(const f16x8a*)&pt[w][l31][16 + h * 8];
      acc[jt][0] = MFMA32(pa0, bv[0][0], acc[jt][0]);
      acc[jt][1] = MFMA32(pa0, bv[1][0], acc[jt][1]);
      acc[jt][0] = MFMA32(pa1, bv[0][1], acc[jt][0]);
      acc[jt][1] = MFMA32(pa1, bv[1][1], acc[jt][1]);
    }

    // stage write for next chunk
    if (t < 15) {
      if (se) *(f16x8a*)&etL[cur ^ 1][sei][sec] = sv;
      else    *(f16x8a*)&ecL[cur ^ 1][scc][sci] = sv;
    }
    __syncthreads();
  }

  // partial[iq][b][j][c] (out^T layout -> coalesced: lanes vary c)
  f16* pb = partial + (size_t)(iq * B + b) * HW * C;
  #pragma unroll
  for (int jt = 0; jt < 2; ++jt)
    #pragma unroll
    for (int cs = 0; cs < 2; ++cs)
      #pragma unroll
      for (int r = 0; r < 16; ++r) {
        int j = jbase + jt * 32 + (r & 3) + 8 * (r >> 2) + 4 * h;
        pb[(size_t)j * C + cs * 32 + l31] = (f16)acc[jt][cs][r];
      }
}

// ---------------- Kernel D: out[c][j] = x + sum_iq partial[iq][j][c] (transpose) ----
__global__ __launch_bounds__(256) void k_reduce(
    const f16* __restrict__ partial, const float* __restrict__ x, float* __restrict__ out)
{
  __shared__ float tile[64][65];
  const int blk = swz_blk();
  const int b = blk >> 6;
  const int j0 = (blk & 63) * 64;
  const int tid = threadIdx.x;
  const int jj = tid >> 2, cq = (tid & 3) * 16;

  float a0[16] = {};
  for (int iq = 0; iq < 8; ++iq) {
    const f16* p = partial + ((size_t)(iq * B + b) * HW + j0 + jj) * C + cq;
    f16x8 v0 = *(const f16x8*)p;
    f16x8 v1 = *(const f16x8*)(p + 8);
    #pragma unroll
    for (int e = 0; e < 8; ++e) { a0[e] += (float)v0[e]; a0[8 + e] += (float)v1[e]; }
  }
  #pragma unroll
  for (int e = 0; e < 16; ++e) tile[jj][cq + e] = a0[e];
  __syncthreads();

  const int c = tid >> 2, jq = (tid & 3) * 16;
  #pragma unroll
  for (int k = 0; k < 4; ++k) {
    size_t idx = ((size_t)b * C + c) * HW + j0 + jq + k * 4;
    float4 xv = *(const float4*)(x + idx);
    float4 ov;
    ov.x = tile[jq + k * 4 + 0][c] + xv.x;
    ov.y = tile[jq + k * 4 + 1][c] + xv.y;
    ov.z = tile[jq + k * 4 + 2][c] + xv.z;
    ov.w = tile[jq + k * 4 + 3][c] + xv.w;
    *(float4*)(out + idx) = ov;
  }
}

extern "C" void kernel_launch(void* const* d_in, const int* in_sizes, int n_in,
                              void* d_out, int out_size, void* d_ws, size_t ws_size,
                              hipStream_t stream) {
  const float* x = (const float*)d_in[0];
  const float* W = (const float*)d_in[1];
  const float* bconv = (const float*)d_in[2];
  float* out = (float*)d_out;

  f16* et16 = (f16*)d_ws;
  f16* ec16 = et16 + (size_t)B * HW * C;
  float* mbuf = (float*)(ec16 + (size_t)B * HW * C);
  float* rlbuf = mbuf + (size_t)B * HW;
  f16* partial = (f16*)(rlbuf + (size_t)B * HW);   // 16 MB; ws total ~20.2 MB

  k_e<<<dim3(256), dim3(256), 0, stream>>>(x, W, bconv, et16, ec16);
  k_stats<<<dim3(512), dim3(512), 0, stream>>>(et16, mbuf, rlbuf);
  k_out<<<dim3(256), dim3(512), 0, stream>>>(et16, ec16, mbuf, rlbuf, partial);
  k_reduce<<<dim3(256), dim3(256), 0, stream>>>(partial, x, out);
}